// Round 2
// baseline (760.469 us; speedup 1.0000x reference)
//
#include <hip/hip_runtime.h>
#include <stdint.h>

#define B_DIM 8
#define T_DIM 1024
#define C_DIM 2048
#define M_DIM (B_DIM * T_DIM)   // 8192 rows = B*T

typedef __bf16 bf16x8 __attribute__((ext_vector_type(8)));
typedef __bf16 bf16x4 __attribute__((ext_vector_type(4)));
typedef float  f32x4  __attribute__((ext_vector_type(4)));

// ---------------------------------------------------------------------------
// async global -> LDS, 16 bytes per lane (global_load_lds_dwordx4).
// LDS dest is wave-uniform base + lane*16 (m104/m108 semantics).
// ---------------------------------------------------------------------------
__device__ __forceinline__ void gld_lds16(const void* g, void* l) {
    __builtin_amdgcn_global_load_lds((__attribute__((address_space(1))) void*)g,
                                     (__attribute__((address_space(3))) void*)l,
                                     16, 0, 0);
}

// ---------------------------------------------------------------------------
// Downcast the 4 weight matrices fp32 -> bf16.  grid (C*C/1024, 4) x 256.
// ---------------------------------------------------------------------------
__global__ __launch_bounds__(256) void cast_w_kernel(
    const float* __restrict__ w0, const float* __restrict__ w1,
    const float* __restrict__ w2, const float* __restrict__ w3,
    __bf16* __restrict__ dst) {
    const float* srcs[4] = {w0, w1, w2, w3};
    const float* s = srcs[blockIdx.y];
    __bf16* d = dst + (size_t)blockIdx.y * (size_t)C_DIM * C_DIM;
    const size_t i = ((size_t)blockIdx.x * 256 + threadIdx.x) * 4;
    f32x4 v = *(const f32x4*)(s + i);
    bf16x4 o;
#pragma unroll
    for (int j = 0; j < 4; ++j) o[j] = (__bf16)v[j];
    *(bf16x4*)(d + i) = o;
}

// ---------------------------------------------------------------------------
// Time-shift mixing: xk/xv/xr = x*m + shift(x)*(1-m).  fp32 in, bf16 out.
// ---------------------------------------------------------------------------
__global__ __launch_bounds__(256) void mix4_kernel(
    const float* __restrict__ x,
    const float* __restrict__ mk, const float* __restrict__ mv,
    const float* __restrict__ mr,
    __bf16* __restrict__ xk, __bf16* __restrict__ xv, __bf16* __restrict__ xr) {
    const size_t idx = ((size_t)blockIdx.x * 256 + threadIdx.x) * 4;
    const int c = (int)(idx & (C_DIM - 1));
    const int t = (int)((idx >> 11) & (T_DIM - 1));   // C_DIM == 2^11

    f32x4 xc = *(const f32x4*)(x + idx);
    f32x4 sh = {0.f, 0.f, 0.f, 0.f};
    if (t != 0) sh = *(const f32x4*)(x + idx - C_DIM);
    f32x4 k4 = *(const f32x4*)(mk + c);
    f32x4 v4 = *(const f32x4*)(mv + c);
    f32x4 r4 = *(const f32x4*)(mr + c);

    bf16x4 ok, ov, orr;
#pragma unroll
    for (int j = 0; j < 4; ++j) {
        float xx = xc[j], ss = sh[j];
        ok[j]  = (__bf16)(xx * k4[j] + ss * (1.f - k4[j]));
        ov[j]  = (__bf16)(xx * v4[j] + ss * (1.f - v4[j]));
        orr[j] = (__bf16)(xx * r4[j] + ss * (1.f - r4[j]));
    }
    *(bf16x4*)(xk + idx) = ok;
    *(bf16x4*)(xv + idx) = ov;
    *(bf16x4*)(xr + idx) = orr;
}

// ---------------------------------------------------------------------------
// m97-style bf16 GEMM, B^T input:  Cout[m][n] = sum_k A[m][k] * W[n][k]
// 128x128 tile, BK=32, 4 waves in 2x2, each wave 64x64 via 4x4 MFMA 16x16x32.
// OUTF32 selects fp32 (final) vs bf16 (intermediate) output.
// ---------------------------------------------------------------------------
template <bool OUTF32>
__global__ __launch_bounds__(256) void gemm_bt(
    const __bf16* __restrict__ A, const __bf16* __restrict__ W,
    void* __restrict__ Cout, int M, int N, int K) {
    __shared__ __align__(16) __bf16 As[128 * 32];
    __shared__ __align__(16) __bf16 Bs[128 * 32];

    const int tid  = threadIdx.x;
    const int lane = tid & 63;
    const int wave = tid >> 6;
    const int row0 = blockIdx.x * 128;
    const int col0 = blockIdx.y * 128;
    const int wm = (wave & 1) * 64;
    const int wn = (wave >> 1) * 64;

    f32x4 acc[4][4] = {};

    // staging: per issue, 256 threads x 16B = 64 rows x 32 cols
    const int sr = tid >> 2;          // row within 64-row chunk
    const int sc = (tid & 3) * 8;     // col (bf16 elements)
    const __bf16* Ap = A + (size_t)(row0 + sr) * K + sc;
    const __bf16* Bp = W + (size_t)(col0 + sr) * K + sc;
    __bf16* AsW = As + wave * 512;    // wave-uniform LDS base (elements)
    __bf16* BsW = Bs + wave * 512;

    // fragment read addresses: A[m=lane&15][k=(lane>>4)*8+j], B likewise by n
    const int mrow  = lane & 15;
    const int khalf = (lane >> 4) * 8;
    const __bf16* ArdA = As + (size_t)(wm + mrow) * 32 + khalf;
    const __bf16* BrdB = Bs + (size_t)(wn + mrow) * 32 + khalf;

    for (int k0 = 0; k0 < K; k0 += 32) {
        __syncthreads();   // previous iter's LDS reads done before overwrite
        gld_lds16(Ap + k0,                   AsW);
        gld_lds16(Ap + k0 + (size_t)64 * K,  AsW + 2048);
        gld_lds16(Bp + k0,                   BsW);
        gld_lds16(Bp + k0 + (size_t)64 * K,  BsW + 2048);
        __syncthreads();   // drains vmcnt before barrier (m97 semantics)

        bf16x8 af[4], bfr[4];
#pragma unroll
        for (int i = 0; i < 4; ++i) af[i]  = *(const bf16x8*)(ArdA + i * 16 * 32);
#pragma unroll
        for (int i = 0; i < 4; ++i) bfr[i] = *(const bf16x8*)(BrdB + i * 16 * 32);
#pragma unroll
        for (int im = 0; im < 4; ++im)
#pragma unroll
            for (int in = 0; in < 4; ++in)
                acc[im][in] = __builtin_amdgcn_mfma_f32_16x16x32_bf16(
                    af[im], bfr[in], acc[im][in], 0, 0, 0);
    }

    // epilogue: D row = (lane>>4)*4 + reg, col = lane&15  (m89-verified)
    const int crow = (lane >> 4) * 4;
    const int ccol = lane & 15;
#pragma unroll
    for (int im = 0; im < 4; ++im)
#pragma unroll
        for (int in = 0; in < 4; ++in)
#pragma unroll
            for (int r = 0; r < 4; ++r) {
                int row = row0 + wm + im * 16 + crow + r;
                int col = col0 + wn + in * 16 + ccol;
                if constexpr (OUTF32) {
                    ((float*)Cout)[(size_t)row * N + col] = acc[im][in][r];
                } else {
                    ((__bf16*)Cout)[(size_t)row * N + col] = (__bf16)acc[im][in][r];
                }
            }
}

// ---------------------------------------------------------------------------
// WKV recurrence (numerically-stabilized) + sigmoid(r) gating.
// One thread per (b, c); sequential over T, loads batched 8 timesteps to
// amortize LLC latency (only 256 waves total -> latency-bound).
// ---------------------------------------------------------------------------
__global__ __launch_bounds__(64) void wkv_gate(
    const __bf16* __restrict__ kbuf, const __bf16* __restrict__ vbuf,
    const __bf16* __restrict__ rbuf, const float* __restrict__ td,
    const float* __restrict__ tf, __bf16* __restrict__ abuf) {
    const int c = blockIdx.x * 64 + threadIdx.x;
    const int b = blockIdx.y;
    const size_t base = (size_t)b * T_DIM * C_DIM + c;

    const float w = -__expf(td[c]);
    const float u = tf[c];
    float num = 0.f, den = 0.f, mx = -1e38f;

    for (int t0 = 0; t0 < T_DIM; t0 += 8) {
        float kt[8], vt[8], rt[8];
#pragma unroll
        for (int j = 0; j < 8; ++j) {
            const size_t idx = base + (size_t)(t0 + j) * C_DIM;
            kt[j] = (float)kbuf[idx];
            vt[j] = (float)vbuf[idx];
            rt[j] = (float)rbuf[idx];
        }
#pragma unroll
        for (int j = 0; j < 8; ++j) {
            // output at t
            float mo  = fmaxf(mx, kt[j] + u);
            float e1  = __expf(mx - mo);
            float e2  = __expf(kt[j] + u - mo);
            float out = (e1 * num + e2 * vt[j]) / (e1 * den + e2);

            // state update
            float ms  = fmaxf(mx + w, kt[j]);
            float e1s = __expf(mx + w - ms);
            float e2s = __expf(kt[j] - ms);
            num = e1s * num + e2s * vt[j];
            den = e1s * den + e2s;
            mx  = ms;

            float sr = 1.f / (1.f + __expf(-rt[j]));
            abuf[base + (size_t)(t0 + j) * C_DIM] = (__bf16)(sr * out);
        }
    }
}

// ---------------------------------------------------------------------------
extern "C" void kernel_launch(void* const* d_in, const int* in_sizes, int n_in,
                              void* d_out, int out_size, void* d_ws, size_t ws_size,
                              hipStream_t stream) {
    (void)in_sizes; (void)n_in; (void)out_size; (void)ws_size;
    const float* x  = (const float*)d_in[0];
    const float* td = (const float*)d_in[1];
    const float* tf = (const float*)d_in[2];
    const float* mk = (const float*)d_in[3];
    const float* mv = (const float*)d_in[4];
    const float* mr = (const float*)d_in[5];
    const float* Wk = (const float*)d_in[6];
    const float* Wv = (const float*)d_in[7];
    const float* Wr = (const float*)d_in[8];
    const float* Wo = (const float*)d_in[9];
    float* out = (float*)d_out;

    const size_t WN = (size_t)C_DIM * C_DIM;    // 4,194,304
    const size_t n  = (size_t)M_DIM * C_DIM;    // 16,777,216

    // ws layout (bf16 elements): [Wk|Wv|Wr|Wo bf16][slot0][slot1][slot2][slot3]
    __bf16* Wb  = (__bf16*)d_ws;
    __bf16* Wkb = Wb;
    __bf16* Wvb = Wb + WN;
    __bf16* Wrb = Wb + 2 * WN;
    __bf16* Wob = Wb + 3 * WN;
    __bf16* xk  = Wb + 4 * WN;                  // slot 0
    __bf16* xv  = xk + n;                       // slot 1
    __bf16* xr  = xv + n;                       // slot 2
    __bf16* kb  = xr + n;                       // slot 3
    __bf16* vb  = xk;                           // reuse slot 0 (xk dead)
    __bf16* rb  = xv;                           // reuse slot 1 (xv dead)
    __bf16* ab  = xr;                           // reuse slot 2 (xr dead)

    cast_w_kernel<<<dim3((unsigned)(WN / 4 / 256), 4), 256, 0, stream>>>(
        Wk, Wv, Wr, Wo, Wb);

    mix4_kernel<<<dim3((unsigned)(n / 4 / 256)), 256, 0, stream>>>(
        x, mk, mv, mr, xk, xv, xr);

    dim3 ggrid(M_DIM / 128, C_DIM / 128);       // 64 x 16 = 1024 blocks
    gemm_bt<false><<<ggrid, 256, 0, stream>>>(xk, Wkb, kb, M_DIM, C_DIM, C_DIM);
    gemm_bt<false><<<ggrid, 256, 0, stream>>>(xv, Wvb, vb, M_DIM, C_DIM, C_DIM);
    gemm_bt<false><<<ggrid, 256, 0, stream>>>(xr, Wrb, rb, M_DIM, C_DIM, C_DIM);

    wkv_gate<<<dim3(C_DIM / 64, B_DIM), 64, 0, stream>>>(kb, vb, rb, td, tf, ab);

    gemm_bt<true><<<ggrid, 256, 0, stream>>>(ab, Wob, out, M_DIM, C_DIM, C_DIM);
}

// Round 3
// 632.677 us; speedup vs baseline: 1.2020x; 1.2020x over previous
//
#include <hip/hip_runtime.h>
#include <stdint.h>

#define B_DIM 8
#define T_DIM 1024
#define C_DIM 2048
#define M_DIM (B_DIM * T_DIM)   // 8192 rows = B*T
#define SEG   16                // segments for wkv scan
#define SEGL  (T_DIM / SEG)     // 64 steps per segment

typedef __bf16 bf16x8 __attribute__((ext_vector_type(8)));
typedef __bf16 bf16x4 __attribute__((ext_vector_type(4)));
typedef float  f32x4  __attribute__((ext_vector_type(4)));

// ---------------------------------------------------------------------------
// async global -> LDS, 16 bytes per lane (global_load_lds_dwordx4).
// LDS dest is wave-uniform base + lane*16 (m104/m108 semantics).
// ---------------------------------------------------------------------------
__device__ __forceinline__ void gld_lds16(const void* g, void* l) {
    __builtin_amdgcn_global_load_lds((__attribute__((address_space(1))) void*)g,
                                     (__attribute__((address_space(3))) void*)l,
                                     16, 0, 0);
}

// ---------------------------------------------------------------------------
// Downcast the 4 weight matrices fp32 -> bf16.  grid (C*C/1024, 4) x 256.
// ---------------------------------------------------------------------------
__global__ __launch_bounds__(256) void cast_w_kernel(
    const float* __restrict__ w0, const float* __restrict__ w1,
    const float* __restrict__ w2, const float* __restrict__ w3,
    __bf16* __restrict__ dst) {
    const float* srcs[4] = {w0, w1, w2, w3};
    const float* s = srcs[blockIdx.y];
    __bf16* d = dst + (size_t)blockIdx.y * (size_t)C_DIM * C_DIM;
    const size_t i = ((size_t)blockIdx.x * 256 + threadIdx.x) * 4;
    f32x4 v = *(const f32x4*)(s + i);
    bf16x4 o;
#pragma unroll
    for (int j = 0; j < 4; ++j) o[j] = (__bf16)v[j];
    *(bf16x4*)(d + i) = o;
}

// ---------------------------------------------------------------------------
// Time-shift mixing: xk/xv/xr = x*m + shift(x)*(1-m).  fp32 in, bf16 out.
// ---------------------------------------------------------------------------
__global__ __launch_bounds__(256) void mix4_kernel(
    const float* __restrict__ x,
    const float* __restrict__ mk, const float* __restrict__ mv,
    const float* __restrict__ mr,
    __bf16* __restrict__ xk, __bf16* __restrict__ xv, __bf16* __restrict__ xr) {
    const size_t idx = ((size_t)blockIdx.x * 256 + threadIdx.x) * 4;
    const int c = (int)(idx & (C_DIM - 1));
    const int t = (int)((idx >> 11) & (T_DIM - 1));   // C_DIM == 2^11

    f32x4 xc = *(const f32x4*)(x + idx);
    f32x4 sh = {0.f, 0.f, 0.f, 0.f};
    if (t != 0) sh = *(const f32x4*)(x + idx - C_DIM);
    f32x4 k4 = *(const f32x4*)(mk + c);
    f32x4 v4 = *(const f32x4*)(mv + c);
    f32x4 r4 = *(const f32x4*)(mr + c);

    bf16x4 ok, ov, orr;
#pragma unroll
    for (int j = 0; j < 4; ++j) {
        float xx = xc[j], ss = sh[j];
        ok[j]  = (__bf16)(xx * k4[j] + ss * (1.f - k4[j]));
        ov[j]  = (__bf16)(xx * v4[j] + ss * (1.f - v4[j]));
        orr[j] = (__bf16)(xx * r4[j] + ss * (1.f - r4[j]));
    }
    *(bf16x4*)(xk + idx) = ok;
    *(bf16x4*)(xv + idx) = ov;
    *(bf16x4*)(xr + idx) = orr;
}

// ---------------------------------------------------------------------------
// m97-style bf16 GEMM, B^T input:  Cout[m][n] = sum_k A[m][k] * W[n][k]
// 128x128 tile, BK=32, 4 waves in 2x2, each wave 64x64 via 4x4 MFMA 16x16x32.
// OUTF32 selects fp32 (final) vs bf16 (intermediate) output.
// ---------------------------------------------------------------------------
template <bool OUTF32>
__global__ __launch_bounds__(256) void gemm_bt(
    const __bf16* __restrict__ A, const __bf16* __restrict__ W,
    void* __restrict__ Cout, int M, int N, int K) {
    __shared__ __align__(16) __bf16 As[128 * 32];
    __shared__ __align__(16) __bf16 Bs[128 * 32];

    const int tid  = threadIdx.x;
    const int lane = tid & 63;
    const int wave = tid >> 6;
    const int row0 = blockIdx.x * 128;
    const int col0 = blockIdx.y * 128;
    const int wm = (wave & 1) * 64;
    const int wn = (wave >> 1) * 64;

    f32x4 acc[4][4] = {};

    // staging: per issue, 256 threads x 16B = 64 rows x 32 cols
    const int sr = tid >> 2;          // row within 64-row chunk
    const int sc = (tid & 3) * 8;     // col (bf16 elements)
    const __bf16* Ap = A + (size_t)(row0 + sr) * K + sc;
    const __bf16* Bp = W + (size_t)(col0 + sr) * K + sc;
    __bf16* AsW = As + wave * 512;    // wave-uniform LDS base (elements)
    __bf16* BsW = Bs + wave * 512;

    // fragment read addresses: A[m=lane&15][k=(lane>>4)*8+j], B likewise by n
    const int mrow  = lane & 15;
    const int khalf = (lane >> 4) * 8;
    const __bf16* ArdA = As + (size_t)(wm + mrow) * 32 + khalf;
    const __bf16* BrdB = Bs + (size_t)(wn + mrow) * 32 + khalf;

    for (int k0 = 0; k0 < K; k0 += 32) {
        __syncthreads();   // previous iter's LDS reads done before overwrite
        gld_lds16(Ap + k0,                   AsW);
        gld_lds16(Ap + k0 + (size_t)64 * K,  AsW + 2048);
        gld_lds16(Bp + k0,                   BsW);
        gld_lds16(Bp + k0 + (size_t)64 * K,  BsW + 2048);
        __syncthreads();   // drains vmcnt before barrier (m97 semantics)

        bf16x8 af[4], bfr[4];
#pragma unroll
        for (int i = 0; i < 4; ++i) af[i]  = *(const bf16x8*)(ArdA + i * 16 * 32);
#pragma unroll
        for (int i = 0; i < 4; ++i) bfr[i] = *(const bf16x8*)(BrdB + i * 16 * 32);
#pragma unroll
        for (int im = 0; im < 4; ++im)
#pragma unroll
            for (int in = 0; in < 4; ++in)
                acc[im][in] = __builtin_amdgcn_mfma_f32_16x16x32_bf16(
                    af[im], bfr[in], acc[im][in], 0, 0, 0);
    }

    // epilogue: D row = (lane>>4)*4 + reg, col = lane&15  (m89-verified)
    const int crow = (lane >> 4) * 4;
    const int ccol = lane & 15;
#pragma unroll
    for (int im = 0; im < 4; ++im)
#pragma unroll
        for (int in = 0; in < 4; ++in)
#pragma unroll
            for (int r = 0; r < 4; ++r) {
                int row = row0 + wm + im * 16 + crow + r;
                int col = col0 + wn + in * 16 + ccol;
                if constexpr (OUTF32) {
                    ((float*)Cout)[(size_t)row * N + col] = acc[im][in][r];
                } else {
                    ((__bf16*)Cout)[(size_t)row * N + col] = (__bf16)acc[im][in][r];
                }
            }
}

// ---------------------------------------------------------------------------
// WKV segmented scan.  State (num, den, mx): stabilized linear recurrence.
// pass1: per (b,c,seg) compute segment aggregate from zero state.
// pass2: per (b,c) sequentially combine aggregates -> incoming state per seg.
// pass3: per (b,c,seg) replay segment from incoming state, emit gated output.
// State layout: [seg][b][c] fp32, coalesced over c.
// ---------------------------------------------------------------------------
__global__ __launch_bounds__(256) void wkv_pass1(
    const __bf16* __restrict__ kbuf, const __bf16* __restrict__ vbuf,
    const float* __restrict__ td,
    float* __restrict__ st_num, float* __restrict__ st_den,
    float* __restrict__ st_m) {
    const int c = blockIdx.x * 256 + threadIdx.x;
    const int b = blockIdx.y;
    const int s = blockIdx.z;
    const size_t base = (size_t)b * T_DIM * C_DIM + (size_t)s * SEGL * C_DIM + c;

    const float w = -__expf(td[c]);
    float num = 0.f, den = 0.f, mx = -1e38f;

    for (int t0 = 0; t0 < SEGL; t0 += 8) {
        float kt[8], vt[8];
#pragma unroll
        for (int j = 0; j < 8; ++j) {
            const size_t idx = base + (size_t)(t0 + j) * C_DIM;
            kt[j] = (float)kbuf[idx];
            vt[j] = (float)vbuf[idx];
        }
#pragma unroll
        for (int j = 0; j < 8; ++j) {
            float ms  = fmaxf(mx + w, kt[j]);
            float e1s = __expf(mx + w - ms);
            float e2s = __expf(kt[j] - ms);
            num = e1s * num + e2s * vt[j];
            den = e1s * den + e2s;
            mx  = ms;
        }
    }
    const size_t sidx = (size_t)s * (B_DIM * C_DIM) + (size_t)b * C_DIM + c;
    st_num[sidx] = num;
    st_den[sidx] = den;
    st_m[sidx]   = mx;
}

__global__ __launch_bounds__(256) void wkv_pass2(
    const float* __restrict__ td,
    float* __restrict__ st_num, float* __restrict__ st_den,
    float* __restrict__ st_m) {
    const int bc = blockIdx.x * 256 + threadIdx.x;   // b*C + c
    const int c  = bc & (C_DIM - 1);
    const float w = -__expf(td[c]);
    const float wL = w * SEGL;

    float num = 0.f, den = 0.f, mx = -1e38f;
    for (int s = 0; s < SEG; ++s) {
        const size_t sidx = (size_t)s * (B_DIM * C_DIM) + bc;
        float na = st_num[sidx], da = st_den[sidx], ma = st_m[sidx];
        // write incoming state for this segment (overwrite aggregate)
        st_num[sidx] = num; st_den[sidx] = den; st_m[sidx] = mx;
        // combine: state <- decay^L(state) + aggregate
        float md = mx + wL;
        float mc = fmaxf(md, ma);
        float e1 = __expf(md - mc);
        float e2 = __expf(ma - mc);
        num = e1 * num + e2 * na;
        den = e1 * den + e2 * da;
        mx  = mc;
    }
}

__global__ __launch_bounds__(256) void wkv_pass3(
    const __bf16* __restrict__ kbuf, const __bf16* __restrict__ vbuf,
    const __bf16* __restrict__ rbuf, const float* __restrict__ td,
    const float* __restrict__ tf,
    const float* __restrict__ st_num, const float* __restrict__ st_den,
    const float* __restrict__ st_m, __bf16* __restrict__ abuf) {
    const int c = blockIdx.x * 256 + threadIdx.x;
    const int b = blockIdx.y;
    const int s = blockIdx.z;
    const size_t base = (size_t)b * T_DIM * C_DIM + (size_t)s * SEGL * C_DIM + c;

    const float w = -__expf(td[c]);
    const float u = tf[c];
    const size_t sidx = (size_t)s * (B_DIM * C_DIM) + (size_t)b * C_DIM + c;
    float num = st_num[sidx], den = st_den[sidx], mx = st_m[sidx];

    for (int t0 = 0; t0 < SEGL; t0 += 8) {
        float kt[8], vt[8], rt[8];
#pragma unroll
        for (int j = 0; j < 8; ++j) {
            const size_t idx = base + (size_t)(t0 + j) * C_DIM;
            kt[j] = (float)kbuf[idx];
            vt[j] = (float)vbuf[idx];
            rt[j] = (float)rbuf[idx];
        }
#pragma unroll
        for (int j = 0; j < 8; ++j) {
            float mo  = fmaxf(mx, kt[j] + u);
            float e1  = __expf(mx - mo);
            float e2  = __expf(kt[j] + u - mo);
            float out = (e1 * num + e2 * vt[j]) / (e1 * den + e2);

            float ms  = fmaxf(mx + w, kt[j]);
            float e1s = __expf(mx + w - ms);
            float e2s = __expf(kt[j] - ms);
            num = e1s * num + e2s * vt[j];
            den = e1s * den + e2s;
            mx  = ms;

            float sr = 1.f / (1.f + __expf(-rt[j]));
            abuf[base + (size_t)(t0 + j) * C_DIM] = (__bf16)(sr * out);
        }
    }
}

// ---------------------------------------------------------------------------
extern "C" void kernel_launch(void* const* d_in, const int* in_sizes, int n_in,
                              void* d_out, int out_size, void* d_ws, size_t ws_size,
                              hipStream_t stream) {
    (void)in_sizes; (void)n_in; (void)out_size; (void)ws_size;
    const float* x  = (const float*)d_in[0];
    const float* td = (const float*)d_in[1];
    const float* tf = (const float*)d_in[2];
    const float* mk = (const float*)d_in[3];
    const float* mv = (const float*)d_in[4];
    const float* mr = (const float*)d_in[5];
    const float* Wk = (const float*)d_in[6];
    const float* Wv = (const float*)d_in[7];
    const float* Wr = (const float*)d_in[8];
    const float* Wo = (const float*)d_in[9];
    float* out = (float*)d_out;

    const size_t WN = (size_t)C_DIM * C_DIM;    // 4,194,304
    const size_t n  = (size_t)M_DIM * C_DIM;    // 16,777,216

    // ws layout (bf16 elements): [Wk|Wv|Wr|Wo bf16][slot0][slot1][slot2][slot3]
    __bf16* Wb  = (__bf16*)d_ws;
    __bf16* Wkb = Wb;
    __bf16* Wvb = Wb + WN;
    __bf16* Wrb = Wb + 2 * WN;
    __bf16* Wob = Wb + 3 * WN;
    __bf16* xk  = Wb + 4 * WN;                  // slot 0
    __bf16* xv  = xk + n;                       // slot 1
    __bf16* xr  = xv + n;                       // slot 2
    __bf16* kb  = xr + n;                       // slot 3
    __bf16* vb  = xk;                           // reuse slot 0 (xk dead)
    __bf16* rb  = xv;                           // reuse slot 1 (xv dead)
    __bf16* ab  = xr;                           // reuse slot 2 (xr dead)

    // WKV state arrays (3 MB) live in the Wkb region: Wkb is dead once the
    // k-GEMM completes, and cast_w rewrites it at the start of every launch.
    float* st_num = (float*)d_ws;
    float* st_den = st_num + (size_t)SEG * B_DIM * C_DIM;
    float* st_m   = st_den + (size_t)SEG * B_DIM * C_DIM;

    cast_w_kernel<<<dim3((unsigned)(WN / 4 / 256), 4), 256, 0, stream>>>(
        Wk, Wv, Wr, Wo, Wb);

    mix4_kernel<<<dim3((unsigned)(n / 4 / 256)), 256, 0, stream>>>(
        x, mk, mv, mr, xk, xv, xr);

    dim3 ggrid(M_DIM / 128, C_DIM / 128);       // 64 x 16 = 1024 blocks
    gemm_bt<false><<<ggrid, 256, 0, stream>>>(xk, Wkb, kb, M_DIM, C_DIM, C_DIM);
    gemm_bt<false><<<ggrid, 256, 0, stream>>>(xv, Wvb, vb, M_DIM, C_DIM, C_DIM);
    gemm_bt<false><<<ggrid, 256, 0, stream>>>(xr, Wrb, rb, M_DIM, C_DIM, C_DIM);

    dim3 wgrid(C_DIM / 256, B_DIM, SEG);        // 8 x 8 x 16 = 1024 blocks
    wkv_pass1<<<wgrid, 256, 0, stream>>>(kb, vb, td, st_num, st_den, st_m);
    wkv_pass2<<<dim3(B_DIM * C_DIM / 256), 256, 0, stream>>>(
        td, st_num, st_den, st_m);
    wkv_pass3<<<wgrid, 256, 0, stream>>>(kb, vb, rb, td, tf,
                                         st_num, st_den, st_m, ab);

    gemm_bt<true><<<ggrid, 256, 0, stream>>>(ab, Wob, out, M_DIM, C_DIM, C_DIM);
}

// Round 4
// 624.726 us; speedup vs baseline: 1.2173x; 1.0127x over previous
//
#include <hip/hip_runtime.h>
#include <stdint.h>

#define B_DIM 8
#define T_DIM 1024
#define C_DIM 2048
#define M_DIM (B_DIM * T_DIM)   // 8192 rows = B*T
#define SEG   32                // segments for wkv scan
#define SEGL  (T_DIM / SEG)     // 32 steps per segment

typedef __bf16 bf16x8 __attribute__((ext_vector_type(8)));
typedef __bf16 bf16x4 __attribute__((ext_vector_type(4)));
typedef float  f32x4  __attribute__((ext_vector_type(4)));

// ---------------------------------------------------------------------------
// async global -> LDS, 16 bytes per lane (global_load_lds_dwordx4).
// LDS dest is wave-uniform base + lane*16 (m104/m108 semantics).
// ---------------------------------------------------------------------------
__device__ __forceinline__ void gld_lds16(const void* g, void* l) {
    __builtin_amdgcn_global_load_lds((__attribute__((address_space(1))) void*)g,
                                     (__attribute__((address_space(3))) void*)l,
                                     16, 0, 0);
}

// ---------------------------------------------------------------------------
// Downcast the 4 weight matrices fp32 -> bf16.  grid (C*C/1024, 4) x 256.
// ---------------------------------------------------------------------------
__global__ __launch_bounds__(256) void cast_w_kernel(
    const float* __restrict__ w0, const float* __restrict__ w1,
    const float* __restrict__ w2, const float* __restrict__ w3,
    __bf16* __restrict__ dst) {
    const float* srcs[4] = {w0, w1, w2, w3};
    const float* s = srcs[blockIdx.y];
    __bf16* d = dst + (size_t)blockIdx.y * (size_t)C_DIM * C_DIM;
    const size_t i = ((size_t)blockIdx.x * 256 + threadIdx.x) * 4;
    f32x4 v = *(const f32x4*)(s + i);
    bf16x4 o;
#pragma unroll
    for (int j = 0; j < 4; ++j) o[j] = (__bf16)v[j];
    *(bf16x4*)(d + i) = o;
}

// ---------------------------------------------------------------------------
// Time-shift mixing: xk/xv/xr = x*m + shift(x)*(1-m).  fp32 in, bf16 out.
// ---------------------------------------------------------------------------
__global__ __launch_bounds__(256) void mix4_kernel(
    const float* __restrict__ x,
    const float* __restrict__ mk, const float* __restrict__ mv,
    const float* __restrict__ mr,
    __bf16* __restrict__ xk, __bf16* __restrict__ xv, __bf16* __restrict__ xr) {
    const size_t idx = ((size_t)blockIdx.x * 256 + threadIdx.x) * 4;
    const int c = (int)(idx & (C_DIM - 1));
    const int t = (int)((idx >> 11) & (T_DIM - 1));   // C_DIM == 2^11

    f32x4 xc = *(const f32x4*)(x + idx);
    f32x4 sh = {0.f, 0.f, 0.f, 0.f};
    if (t != 0) sh = *(const f32x4*)(x + idx - C_DIM);
    f32x4 k4 = *(const f32x4*)(mk + c);
    f32x4 v4 = *(const f32x4*)(mv + c);
    f32x4 r4 = *(const f32x4*)(mr + c);

    bf16x4 ok, ov, orr;
#pragma unroll
    for (int j = 0; j < 4; ++j) {
        float xx = xc[j], ss = sh[j];
        ok[j]  = (__bf16)(xx * k4[j] + ss * (1.f - k4[j]));
        ov[j]  = (__bf16)(xx * v4[j] + ss * (1.f - v4[j]));
        orr[j] = (__bf16)(xx * r4[j] + ss * (1.f - r4[j]));
    }
    *(bf16x4*)(xk + idx) = ok;
    *(bf16x4*)(xv + idx) = ov;
    *(bf16x4*)(xr + idx) = orr;
}

// ---------------------------------------------------------------------------
// m97-style bf16 GEMM, B^T input:  Cout[m][n] = sum_k A[m][k] * W[n][k]
// 128x128 tile, BK=32, 4 waves in 2x2, each wave 64x64 via 4x4 MFMA 16x16x32.
//
// LDS layout is XOR-swizzled to kill ds_read_b128 bank conflicts: the 8-elem
// k-group g of row r lives at group-slot gs = g ^ ((r>>1)&3).  The swizzle is
// applied on the GLOBAL address side of the staging (global_load_lds forces
// LDS dest = base + lane*16), so DMA writes stay contiguous/conflict-free and
// fragment reads spread 16 same-quarter rows over 8 bank-quads (2-way = free
// per m136, vs 8-way before).
// ---------------------------------------------------------------------------
template <bool OUTF32>
__global__ __launch_bounds__(256) void gemm_bt(
    const __bf16* __restrict__ A, const __bf16* __restrict__ W,
    void* __restrict__ Cout, int M, int N, int K) {
    __shared__ __align__(16) __bf16 As[128 * 32];
    __shared__ __align__(16) __bf16 Bs[128 * 32];

    const int tid  = threadIdx.x;
    const int lane = tid & 63;
    const int wave = tid >> 6;
    const int row0 = blockIdx.x * 128;
    const int col0 = blockIdx.y * 128;
    const int wm = (wave & 1) * 64;
    const int wn = (wave >> 1) * 64;

    f32x4 acc[4][4] = {};

    // staging: per issue, 256 threads x 16B = 64 rows x 32 cols.
    // lane's LDS slot = (row = tid>>2, group-slot gs = tid&3); it must fetch
    // global k-group g = gs ^ ((row>>1)&3).
    const int sr = tid >> 2;
    const int gs = tid & 3;
    const int sc = (gs ^ ((sr >> 1) & 3)) * 8;      // global col (elements)
    const __bf16* Ap = A + (size_t)(row0 + sr) * K + sc;
    const __bf16* Bp = W + (size_t)(col0 + sr) * K + sc;
    __bf16* AsW = As + wave * 512;    // wave-uniform LDS base (elements)
    __bf16* BsW = Bs + wave * 512;

    // fragment reads: lane = m + 16*q holds k = q*8..q*8+7 of row wm+m+i*16.
    // swizzled LDS group-slot = q ^ ((row>>1)&3); i*16 and wm preserve
    // (row>>1)&3, so the offset is loop-invariant.
    const int mrow = lane & 15;
    const int q    = lane >> 4;
    const int swz  = (q ^ ((mrow >> 1) & 3)) * 8;
    const __bf16* ArdA = As + (size_t)(wm + mrow) * 32 + swz;
    const __bf16* BrdB = Bs + (size_t)(wn + mrow) * 32 + swz;

    for (int k0 = 0; k0 < K; k0 += 32) {
        __syncthreads();   // previous iter's LDS reads done before overwrite
        gld_lds16(Ap + k0,                   AsW);
        gld_lds16(Ap + k0 + (size_t)64 * K,  AsW + 2048);
        gld_lds16(Bp + k0,                   BsW);
        gld_lds16(Bp + k0 + (size_t)64 * K,  BsW + 2048);
        __syncthreads();   // drains vmcnt before barrier (m97 semantics)

        bf16x8 af[4], bfr[4];
#pragma unroll
        for (int i = 0; i < 4; ++i) af[i]  = *(const bf16x8*)(ArdA + i * 16 * 32);
#pragma unroll
        for (int i = 0; i < 4; ++i) bfr[i] = *(const bf16x8*)(BrdB + i * 16 * 32);
#pragma unroll
        for (int im = 0; im < 4; ++im)
#pragma unroll
            for (int in = 0; in < 4; ++in)
                acc[im][in] = __builtin_amdgcn_mfma_f32_16x16x32_bf16(
                    af[im], bfr[in], acc[im][in], 0, 0, 0);
    }

    // epilogue: D row = (lane>>4)*4 + reg, col = lane&15  (m89-verified)
    const int crow = (lane >> 4) * 4;
    const int ccol = lane & 15;
#pragma unroll
    for (int im = 0; im < 4; ++im)
#pragma unroll
        for (int in = 0; in < 4; ++in)
#pragma unroll
            for (int r = 0; r < 4; ++r) {
                int row = row0 + wm + im * 16 + crow + r;
                int col = col0 + wn + in * 16 + ccol;
                if constexpr (OUTF32) {
                    ((float*)Cout)[(size_t)row * N + col] = acc[im][in][r];
                } else {
                    ((__bf16*)Cout)[(size_t)row * N + col] = (__bf16)acc[im][in][r];
                }
            }
}

// ---------------------------------------------------------------------------
// WKV segmented scan.  State (num, den, mx): stabilized linear recurrence.
// pass1: per (b,c,seg) compute segment aggregate from zero state.
// pass2: per (b,c) sequentially combine aggregates -> incoming state per seg.
// pass3: per (b,c,seg) replay segment from incoming state, emit gated output.
// State layout: [seg][b][c] fp32, coalesced over c.
// ---------------------------------------------------------------------------
__global__ __launch_bounds__(256) void wkv_pass1(
    const __bf16* __restrict__ kbuf, const __bf16* __restrict__ vbuf,
    const float* __restrict__ td,
    float* __restrict__ st_num, float* __restrict__ st_den,
    float* __restrict__ st_m) {
    const int c = blockIdx.x * 256 + threadIdx.x;
    const int b = blockIdx.y;
    const int s = blockIdx.z;
    const size_t base = (size_t)b * T_DIM * C_DIM + (size_t)s * SEGL * C_DIM + c;

    const float w = -__expf(td[c]);
    float num = 0.f, den = 0.f, mx = -1e38f;

    for (int t0 = 0; t0 < SEGL; t0 += 8) {
        float kt[8], vt[8];
#pragma unroll
        for (int j = 0; j < 8; ++j) {
            const size_t idx = base + (size_t)(t0 + j) * C_DIM;
            kt[j] = (float)kbuf[idx];
            vt[j] = (float)vbuf[idx];
        }
#pragma unroll
        for (int j = 0; j < 8; ++j) {
            float ms  = fmaxf(mx + w, kt[j]);
            float e1s = __expf(mx + w - ms);
            float e2s = __expf(kt[j] - ms);
            num = e1s * num + e2s * vt[j];
            den = e1s * den + e2s;
            mx  = ms;
        }
    }
    const size_t sidx = (size_t)s * (B_DIM * C_DIM) + (size_t)b * C_DIM + c;
    st_num[sidx] = num;
    st_den[sidx] = den;
    st_m[sidx]   = mx;
}

__global__ __launch_bounds__(256) void wkv_pass2(
    const float* __restrict__ td,
    float* __restrict__ st_num, float* __restrict__ st_den,
    float* __restrict__ st_m) {
    const int bc = blockIdx.x * 256 + threadIdx.x;   // b*C + c
    const int c  = bc & (C_DIM - 1);
    const float w = -__expf(td[c]);
    const float wL = w * SEGL;

    float num = 0.f, den = 0.f, mx = -1e38f;
    for (int s = 0; s < SEG; ++s) {
        const size_t sidx = (size_t)s * (B_DIM * C_DIM) + bc;
        float na = st_num[sidx], da = st_den[sidx], ma = st_m[sidx];
        // write incoming state for this segment (overwrite aggregate)
        st_num[sidx] = num; st_den[sidx] = den; st_m[sidx] = mx;
        // combine: state <- decay^L(state) + aggregate
        float md = mx + wL;
        float mc = fmaxf(md, ma);
        float e1 = __expf(md - mc);
        float e2 = __expf(ma - mc);
        num = e1 * num + e2 * na;
        den = e1 * den + e2 * da;
        mx  = mc;
    }
}

__global__ __launch_bounds__(256) void wkv_pass3(
    const __bf16* __restrict__ kbuf, const __bf16* __restrict__ vbuf,
    const __bf16* __restrict__ rbuf, const float* __restrict__ td,
    const float* __restrict__ tf,
    const float* __restrict__ st_num, const float* __restrict__ st_den,
    const float* __restrict__ st_m, __bf16* __restrict__ abuf) {
    const int c = blockIdx.x * 256 + threadIdx.x;
    const int b = blockIdx.y;
    const int s = blockIdx.z;
    const size_t base = (size_t)b * T_DIM * C_DIM + (size_t)s * SEGL * C_DIM + c;

    const float w = -__expf(td[c]);
    const float u = tf[c];
    const size_t sidx = (size_t)s * (B_DIM * C_DIM) + (size_t)b * C_DIM + c;
    float num = st_num[sidx], den = st_den[sidx], mx = st_m[sidx];

    for (int t0 = 0; t0 < SEGL; t0 += 8) {
        float kt[8], vt[8], rt[8];
#pragma unroll
        for (int j = 0; j < 8; ++j) {
            const size_t idx = base + (size_t)(t0 + j) * C_DIM;
            kt[j] = (float)kbuf[idx];
            vt[j] = (float)vbuf[idx];
            rt[j] = (float)rbuf[idx];
        }
#pragma unroll
        for (int j = 0; j < 8; ++j) {
            float mo  = fmaxf(mx, kt[j] + u);
            float e1  = __expf(mx - mo);
            float e2  = __expf(kt[j] + u - mo);
            float out = (e1 * num + e2 * vt[j]) / (e1 * den + e2);

            float ms  = fmaxf(mx + w, kt[j]);
            float e1s = __expf(mx + w - ms);
            float e2s = __expf(kt[j] - ms);
            num = e1s * num + e2s * vt[j];
            den = e1s * den + e2s;
            mx  = ms;

            float sr = 1.f / (1.f + __expf(-rt[j]));
            abuf[base + (size_t)(t0 + j) * C_DIM] = (__bf16)(sr * out);
        }
    }
}

// ---------------------------------------------------------------------------
extern "C" void kernel_launch(void* const* d_in, const int* in_sizes, int n_in,
                              void* d_out, int out_size, void* d_ws, size_t ws_size,
                              hipStream_t stream) {
    (void)in_sizes; (void)n_in; (void)out_size; (void)ws_size;
    const float* x  = (const float*)d_in[0];
    const float* td = (const float*)d_in[1];
    const float* tf = (const float*)d_in[2];
    const float* mk = (const float*)d_in[3];
    const float* mv = (const float*)d_in[4];
    const float* mr = (const float*)d_in[5];
    const float* Wk = (const float*)d_in[6];
    const float* Wv = (const float*)d_in[7];
    const float* Wr = (const float*)d_in[8];
    const float* Wo = (const float*)d_in[9];
    float* out = (float*)d_out;

    const size_t WN = (size_t)C_DIM * C_DIM;    // 4,194,304
    const size_t n  = (size_t)M_DIM * C_DIM;    // 16,777,216

    // ws layout (bf16 elements): [Wk|Wv|Wr|Wo bf16][slot0][slot1][slot2][slot3]
    __bf16* Wb  = (__bf16*)d_ws;
    __bf16* Wkb = Wb;
    __bf16* Wvb = Wb + WN;
    __bf16* Wrb = Wb + 2 * WN;
    __bf16* Wob = Wb + 3 * WN;
    __bf16* xk  = Wb + 4 * WN;                  // slot 0
    __bf16* xv  = xk + n;                       // slot 1
    __bf16* xr  = xv + n;                       // slot 2
    __bf16* kb  = xr + n;                       // slot 3
    __bf16* vb  = xk;                           // reuse slot 0 (xk dead)
    __bf16* rb  = xv;                           // reuse slot 1 (xv dead)
    __bf16* ab  = xr;                           // reuse slot 2 (xr dead)

    // WKV state arrays (6.3 MB) live in the Wkb region: Wkb is dead once the
    // k-GEMM completes, and cast_w rewrites it at the start of every launch.
    float* st_num = (float*)d_ws;
    float* st_den = st_num + (size_t)SEG * B_DIM * C_DIM;
    float* st_m   = st_den + (size_t)SEG * B_DIM * C_DIM;

    cast_w_kernel<<<dim3((unsigned)(WN / 4 / 256), 4), 256, 0, stream>>>(
        Wk, Wv, Wr, Wo, Wb);

    mix4_kernel<<<dim3((unsigned)(n / 4 / 256)), 256, 0, stream>>>(
        x, mk, mv, mr, xk, xv, xr);

    dim3 ggrid(M_DIM / 128, C_DIM / 128);       // 64 x 16 = 1024 blocks
    gemm_bt<false><<<ggrid, 256, 0, stream>>>(xk, Wkb, kb, M_DIM, C_DIM, C_DIM);
    gemm_bt<false><<<ggrid, 256, 0, stream>>>(xv, Wvb, vb, M_DIM, C_DIM, C_DIM);
    gemm_bt<false><<<ggrid, 256, 0, stream>>>(xr, Wrb, rb, M_DIM, C_DIM, C_DIM);

    dim3 wgrid(C_DIM / 256, B_DIM, SEG);        // 8 x 8 x 32 = 2048 blocks
    wkv_pass1<<<wgrid, 256, 0, stream>>>(kb, vb, td, st_num, st_den, st_m);
    wkv_pass2<<<dim3(B_DIM * C_DIM / 256), 256, 0, stream>>>(
        td, st_num, st_den, st_m);
    wkv_pass3<<<wgrid, 256, 0, stream>>>(kb, vb, rb, td, tf,
                                         st_num, st_den, st_m, ab);

    gemm_bt<true><<<ggrid, 256, 0, stream>>>(ab, Wob, out, M_DIM, C_DIM, C_DIM);
}

// Round 5
// 579.759 us; speedup vs baseline: 1.3117x; 1.0776x over previous
//
#include <hip/hip_runtime.h>
#include <stdint.h>

#define B_DIM 8
#define T_DIM 1024
#define C_DIM 2048
#define M_DIM (B_DIM * T_DIM)   // 8192 rows = B*T
#define SEG   32                // segments for wkv scan
#define SEGL  (T_DIM / SEG)     // 32 steps per segment

typedef __bf16 bf16x8 __attribute__((ext_vector_type(8)));
typedef __bf16 bf16x4 __attribute__((ext_vector_type(4)));
typedef float  f32x4  __attribute__((ext_vector_type(4)));

// ---------------------------------------------------------------------------
// async global -> LDS, 16 bytes per lane (global_load_lds_dwordx4).
// LDS dest is wave-uniform base + lane*16 (m104/m108 semantics).
// ---------------------------------------------------------------------------
__device__ __forceinline__ void gld_lds16(const void* g, void* l) {
    __builtin_amdgcn_global_load_lds((__attribute__((address_space(1))) void*)g,
                                     (__attribute__((address_space(3))) void*)l,
                                     16, 0, 0);
}

// ---------------------------------------------------------------------------
// Downcast the 4 weight matrices fp32 -> bf16.  grid (C*C/1024, 4) x 256.
// ---------------------------------------------------------------------------
__global__ __launch_bounds__(256) void cast_w_kernel(
    const float* __restrict__ w0, const float* __restrict__ w1,
    const float* __restrict__ w2, const float* __restrict__ w3,
    __bf16* __restrict__ dst) {
    const float* srcs[4] = {w0, w1, w2, w3};
    const float* s = srcs[blockIdx.y];
    __bf16* d = dst + (size_t)blockIdx.y * (size_t)C_DIM * C_DIM;
    const size_t i = ((size_t)blockIdx.x * 256 + threadIdx.x) * 4;
    f32x4 v = *(const f32x4*)(s + i);
    bf16x4 o;
#pragma unroll
    for (int j = 0; j < 4; ++j) o[j] = (__bf16)v[j];
    *(bf16x4*)(d + i) = o;
}

// ---------------------------------------------------------------------------
// Time-shift mixing: xk/xv/xr = x*m + shift(x)*(1-m).  fp32 in, bf16 out.
// ---------------------------------------------------------------------------
__global__ __launch_bounds__(256) void mix4_kernel(
    const float* __restrict__ x,
    const float* __restrict__ mk, const float* __restrict__ mv,
    const float* __restrict__ mr,
    __bf16* __restrict__ xk, __bf16* __restrict__ xv, __bf16* __restrict__ xr) {
    const size_t idx = ((size_t)blockIdx.x * 256 + threadIdx.x) * 4;
    const int c = (int)(idx & (C_DIM - 1));
    const int t = (int)((idx >> 11) & (T_DIM - 1));   // C_DIM == 2^11

    f32x4 xc = *(const f32x4*)(x + idx);
    f32x4 sh = {0.f, 0.f, 0.f, 0.f};
    if (t != 0) sh = *(const f32x4*)(x + idx - C_DIM);
    f32x4 k4 = *(const f32x4*)(mk + c);
    f32x4 v4 = *(const f32x4*)(mv + c);
    f32x4 r4 = *(const f32x4*)(mr + c);

    bf16x4 ok, ov, orr;
#pragma unroll
    for (int j = 0; j < 4; ++j) {
        float xx = xc[j], ss = sh[j];
        ok[j]  = (__bf16)(xx * k4[j] + ss * (1.f - k4[j]));
        ov[j]  = (__bf16)(xx * v4[j] + ss * (1.f - v4[j]));
        orr[j] = (__bf16)(xx * r4[j] + ss * (1.f - r4[j]));
    }
    *(bf16x4*)(xk + idx) = ok;
    *(bf16x4*)(xv + idx) = ov;
    *(bf16x4*)(xr + idx) = orr;
}

// ---------------------------------------------------------------------------
// bf16 GEMM, B^T input:  Cout[m][n] = sum_k A[m][k] * W[n][k]
// 128x128 tile, BK=64 (one barrier pair per 64-K: half the vmcnt drains of
// the BK=32 version — R4 showed the drain, not LDS conflicts, is the limit).
// 4 waves in 2x2, each wave 64x64 via 4x4 MFMA 16x16x32, two k-halves.
//
// LDS XOR swizzle: 8-elem k-group g of row r lives at slot g ^ (r&7).
// Applied on the GLOBAL side of the staging (global_load_lds forces LDS
// dest = base + lane*16), so DMA writes stay contiguous and ds_read_b128
// fragment reads are conflict-free (2-way max per 16-lane batch; R4
// measured exactly 0 conflict cycles with the same construction).
// ---------------------------------------------------------------------------
template <bool OUTF32>
__global__ __launch_bounds__(256) void gemm_bt(
    const __bf16* __restrict__ A, const __bf16* __restrict__ W,
    void* __restrict__ Cout, int M, int N, int K) {
    __shared__ __align__(16) __bf16 As[128 * 64];   // 16 KB
    __shared__ __align__(16) __bf16 Bs[128 * 64];   // 16 KB

    const int tid  = threadIdx.x;
    const int lane = tid & 63;
    const int wave = tid >> 6;
    const int row0 = blockIdx.x * 128;
    const int col0 = blockIdx.y * 128;
    const int wm = (wave & 1) * 64;
    const int wn = (wave >> 1) * 64;

    f32x4 acc[4][4] = {};

    // staging: per issue, 256 threads x 16B = 4 KB = 32 rows x 128 B.
    // lane's LDS slot = (row sr = tid>>3, group gs = tid&7); it fetches
    // global k-group g = gs ^ (sr&7).  Issue j advances rows by 32 (≡0 mod 8,
    // swizzle invariant) -> global +32j*K, LDS +2048j elements.
    const int sr = tid >> 3;
    const int sc = ((tid & 7) ^ (sr & 7)) * 8;      // global col (elements)
    const __bf16* Ap = A + (size_t)(row0 + sr) * K + sc;
    const __bf16* Bp = W + (size_t)(col0 + sr) * K + sc;
    __bf16* AsW = As + wave * 512;    // wave-uniform LDS base (elements)
    __bf16* BsW = Bs + wave * 512;

    const int mrow = lane & 15;
    const int q    = lane >> 4;

    for (int k0 = 0; k0 < K; k0 += 64) {
        __syncthreads();   // previous iter's LDS reads done before overwrite
#pragma unroll
        for (int j = 0; j < 4; ++j) {
            gld_lds16(Ap + k0 + (size_t)(32 * j) * K, AsW + 2048 * j);
            gld_lds16(Bp + k0 + (size_t)(32 * j) * K, BsW + 2048 * j);
        }
        __syncthreads();   // drains vmcnt before barrier

#pragma unroll
        for (int kk = 0; kk < 2; ++kk) {
            // row R = wm+mrow+16i: R&7 == mrow&7, so swz is i-invariant.
            const int swz = ((q + 4 * kk) ^ (mrow & 7)) * 8;
            bf16x8 af[4], bfr[4];
#pragma unroll
            for (int i = 0; i < 4; ++i)
                af[i]  = *(const bf16x8*)(As + (size_t)(wm + mrow + i * 16) * 64 + swz);
#pragma unroll
            for (int i = 0; i < 4; ++i)
                bfr[i] = *(const bf16x8*)(Bs + (size_t)(wn + mrow + i * 16) * 64 + swz);
#pragma unroll
            for (int im = 0; im < 4; ++im)
#pragma unroll
                for (int in = 0; in < 4; ++in)
                    acc[im][in] = __builtin_amdgcn_mfma_f32_16x16x32_bf16(
                        af[im], bfr[in], acc[im][in], 0, 0, 0);
        }
    }

    // epilogue: D row = (lane>>4)*4 + reg, col = lane&15  (m89-verified)
    const int crow = (lane >> 4) * 4;
    const int ccol = lane & 15;
#pragma unroll
    for (int im = 0; im < 4; ++im)
#pragma unroll
        for (int in = 0; in < 4; ++in)
#pragma unroll
            for (int r = 0; r < 4; ++r) {
                int row = row0 + wm + im * 16 + crow + r;
                int col = col0 + wn + in * 16 + ccol;
                if constexpr (OUTF32) {
                    ((float*)Cout)[(size_t)row * N + col] = acc[im][in][r];
                } else {
                    ((__bf16*)Cout)[(size_t)row * N + col] = (__bf16)acc[im][in][r];
                }
            }
}

// ---------------------------------------------------------------------------
// WKV segmented scan.  State (num, den, mx): stabilized linear recurrence.
// pass1: per (b,c,seg) compute segment aggregate from zero state.
// pass2: per (b,c) sequentially combine aggregates -> incoming state per seg.
// pass3: per (b,c,seg) replay segment from incoming state, emit gated output.
// State layout: [seg][b][c] fp32, coalesced over c.
// ---------------------------------------------------------------------------
__global__ __launch_bounds__(256) void wkv_pass1(
    const __bf16* __restrict__ kbuf, const __bf16* __restrict__ vbuf,
    const float* __restrict__ td,
    float* __restrict__ st_num, float* __restrict__ st_den,
    float* __restrict__ st_m) {
    const int c = blockIdx.x * 256 + threadIdx.x;
    const int b = blockIdx.y;
    const int s = blockIdx.z;
    const size_t base = (size_t)b * T_DIM * C_DIM + (size_t)s * SEGL * C_DIM + c;

    const float w = -__expf(td[c]);
    float num = 0.f, den = 0.f, mx = -1e38f;

    for (int t0 = 0; t0 < SEGL; t0 += 8) {
        float kt[8], vt[8];
#pragma unroll
        for (int j = 0; j < 8; ++j) {
            const size_t idx = base + (size_t)(t0 + j) * C_DIM;
            kt[j] = (float)kbuf[idx];
            vt[j] = (float)vbuf[idx];
        }
#pragma unroll
        for (int j = 0; j < 8; ++j) {
            float ms  = fmaxf(mx + w, kt[j]);
            float e1s = __expf(mx + w - ms);
            float e2s = __expf(kt[j] - ms);
            num = e1s * num + e2s * vt[j];
            den = e1s * den + e2s;
            mx  = ms;
        }
    }
    const size_t sidx = (size_t)s * (B_DIM * C_DIM) + (size_t)b * C_DIM + c;
    st_num[sidx] = num;
    st_den[sidx] = den;
    st_m[sidx]   = mx;
}

__global__ __launch_bounds__(256) void wkv_pass2(
    const float* __restrict__ td,
    float* __restrict__ st_num, float* __restrict__ st_den,
    float* __restrict__ st_m) {
    const int bc = blockIdx.x * 256 + threadIdx.x;   // b*C + c
    const int c  = bc & (C_DIM - 1);
    const float w = -__expf(td[c]);
    const float wL = w * SEGL;

    float num = 0.f, den = 0.f, mx = -1e38f;
    for (int s = 0; s < SEG; ++s) {
        const size_t sidx = (size_t)s * (B_DIM * C_DIM) + bc;
        float na = st_num[sidx], da = st_den[sidx], ma = st_m[sidx];
        // write incoming state for this segment (overwrite aggregate)
        st_num[sidx] = num; st_den[sidx] = den; st_m[sidx] = mx;
        // combine: state <- decay^L(state) + aggregate
        float md = mx + wL;
        float mc = fmaxf(md, ma);
        float e1 = __expf(md - mc);
        float e2 = __expf(ma - mc);
        num = e1 * num + e2 * na;
        den = e1 * den + e2 * da;
        mx  = mc;
    }
}

__global__ __launch_bounds__(256) void wkv_pass3(
    const __bf16* __restrict__ kbuf, const __bf16* __restrict__ vbuf,
    const __bf16* __restrict__ rbuf, const float* __restrict__ td,
    const float* __restrict__ tf,
    const float* __restrict__ st_num, const float* __restrict__ st_den,
    const float* __restrict__ st_m, __bf16* __restrict__ abuf) {
    const int c = blockIdx.x * 256 + threadIdx.x;
    const int b = blockIdx.y;
    const int s = blockIdx.z;
    const size_t base = (size_t)b * T_DIM * C_DIM + (size_t)s * SEGL * C_DIM + c;

    const float w = -__expf(td[c]);
    const float u = tf[c];
    const size_t sidx = (size_t)s * (B_DIM * C_DIM) + (size_t)b * C_DIM + c;
    float num = st_num[sidx], den = st_den[sidx], mx = st_m[sidx];

    for (int t0 = 0; t0 < SEGL; t0 += 8) {
        float kt[8], vt[8], rt[8];
#pragma unroll
        for (int j = 0; j < 8; ++j) {
            const size_t idx = base + (size_t)(t0 + j) * C_DIM;
            kt[j] = (float)kbuf[idx];
            vt[j] = (float)vbuf[idx];
            rt[j] = (float)rbuf[idx];
        }
#pragma unroll
        for (int j = 0; j < 8; ++j) {
            float mo  = fmaxf(mx, kt[j] + u);
            float e1  = __expf(mx - mo);
            float e2  = __expf(kt[j] + u - mo);
            float out = (e1 * num + e2 * vt[j]) / (e1 * den + e2);

            float ms  = fmaxf(mx + w, kt[j]);
            float e1s = __expf(mx + w - ms);
            float e2s = __expf(kt[j] - ms);
            num = e1s * num + e2s * vt[j];
            den = e1s * den + e2s;
            mx  = ms;

            float sr = 1.f / (1.f + __expf(-rt[j]));
            abuf[base + (size_t)(t0 + j) * C_DIM] = (__bf16)(sr * out);
        }
    }
}

// ---------------------------------------------------------------------------
extern "C" void kernel_launch(void* const* d_in, const int* in_sizes, int n_in,
                              void* d_out, int out_size, void* d_ws, size_t ws_size,
                              hipStream_t stream) {
    (void)in_sizes; (void)n_in; (void)out_size; (void)ws_size;
    const float* x  = (const float*)d_in[0];
    const float* td = (const float*)d_in[1];
    const float* tf = (const float*)d_in[2];
    const float* mk = (const float*)d_in[3];
    const float* mv = (const float*)d_in[4];
    const float* mr = (const float*)d_in[5];
    const float* Wk = (const float*)d_in[6];
    const float* Wv = (const float*)d_in[7];
    const float* Wr = (const float*)d_in[8];
    const float* Wo = (const float*)d_in[9];
    float* out = (float*)d_out;

    const size_t WN = (size_t)C_DIM * C_DIM;    // 4,194,304
    const size_t n  = (size_t)M_DIM * C_DIM;    // 16,777,216

    // ws layout (bf16 elements): [Wk|Wv|Wr|Wo bf16][slot0][slot1][slot2][slot3]
    __bf16* Wb  = (__bf16*)d_ws;
    __bf16* Wkb = Wb;
    __bf16* Wvb = Wb + WN;
    __bf16* Wrb = Wb + 2 * WN;
    __bf16* Wob = Wb + 3 * WN;
    __bf16* xk  = Wb + 4 * WN;                  // slot 0
    __bf16* xv  = xk + n;                       // slot 1
    __bf16* xr  = xv + n;                       // slot 2
    __bf16* kb  = xr + n;                       // slot 3
    __bf16* vb  = xk;                           // reuse slot 0 (xk dead)
    __bf16* rb  = xv;                           // reuse slot 1 (xv dead)
    __bf16* ab  = xr;                           // reuse slot 2 (xr dead)

    // WKV state arrays (6.3 MB) live in the Wkb region: Wkb is dead once the
    // k-GEMM completes, and cast_w rewrites it at the start of every launch.
    float* st_num = (float*)d_ws;
    float* st_den = st_num + (size_t)SEG * B_DIM * C_DIM;
    float* st_m   = st_den + (size_t)SEG * B_DIM * C_DIM;

    cast_w_kernel<<<dim3((unsigned)(WN / 4 / 256), 4), 256, 0, stream>>>(
        Wk, Wv, Wr, Wo, Wb);

    mix4_kernel<<<dim3((unsigned)(n / 4 / 256)), 256, 0, stream>>>(
        x, mk, mv, mr, xk, xv, xr);

    dim3 ggrid(M_DIM / 128, C_DIM / 128);       // 64 x 16 = 1024 blocks
    gemm_bt<false><<<ggrid, 256, 0, stream>>>(xk, Wkb, kb, M_DIM, C_DIM, C_DIM);
    gemm_bt<false><<<ggrid, 256, 0, stream>>>(xv, Wvb, vb, M_DIM, C_DIM, C_DIM);
    gemm_bt<false><<<ggrid, 256, 0, stream>>>(xr, Wrb, rb, M_DIM, C_DIM, C_DIM);

    dim3 wgrid(C_DIM / 256, B_DIM, SEG);        // 8 x 8 x 32 = 2048 blocks
    wkv_pass1<<<wgrid, 256, 0, stream>>>(kb, vb, td, st_num, st_den, st_m);
    wkv_pass2<<<dim3(B_DIM * C_DIM / 256), 256, 0, stream>>>(
        td, st_num, st_den, st_m);
    wkv_pass3<<<wgrid, 256, 0, stream>>>(kb, vb, rb, td, tf,
                                         st_num, st_den, st_m, ab);

    gemm_bt<true><<<ggrid, 256, 0, stream>>>(ab, Wob, out, M_DIM, C_DIM, C_DIM);
}